// Round 8
// baseline (788.538 us; speedup 1.0000x reference)
//
#include <hip/hip_runtime.h>
#include <hip/hip_bf16.h>
#include <cfloat>

typedef __attribute__((ext_vector_type(8))) short bf16x8;
typedef __attribute__((ext_vector_type(4))) float f32x4;

#define M_DIM 8192
#define N_DIM 4096
#define K_DIM 4096

__device__ inline ushort f2bf(float f) {
    unsigned u = __float_as_uint(f);
    unsigned r = (u + 0x7FFFu + ((u >> 16) & 1u)) >> 16;
    return (ushort)r;
}

// swizzle: XOR 16B-slot index (bits 4-6) with row low bits (bits 7-9). Involution.
#define SWZ(x) ((x) ^ ((((x) >> 7) & 7) << 4))

// ---------------- kernel 1: weight 4-bit group-128 quant-dequant -> bf16 ----------------
__global__ __launch_bounds__(256) void w_dequant(const float* __restrict__ w,
                                                 ushort* __restrict__ wq) {
    int g = blockIdx.x * 4 + (threadIdx.x >> 6);
    int lane = threadIdx.x & 63;
    const float* src = w + (size_t)g * 128;
    float2 v = *(const float2*)(src + lane * 2);
    float mn = fminf(v.x, v.y), mx = fmaxf(v.x, v.y);
#pragma unroll
    for (int s = 1; s < 64; s <<= 1) {
        mn = fminf(mn, __shfl_xor(mn, s));
        mx = fmaxf(mx, __shfl_xor(mx, s));
    }
    float scale = (mx - mn) / 15.0f;
    float zero  = -8.0f - rintf(mn / scale);
    float q0 = fminf(fmaxf(rintf(v.x / scale) + zero, -8.0f), 7.0f);
    float q1 = fminf(fmaxf(rintf(v.y / scale) + zero, -8.0f), 7.0f);
    ushort2 o;
    o.x = f2bf((q0 - zero) * scale);
    o.y = f2bf((q1 - zero) * scale);
    *(ushort2*)(wq + (size_t)g * 128 + lane * 2) = o;
}

// ---------------- kernel 2: per-row int8 act quant-dequant -> bf16 ----------------
__global__ __launch_bounds__(256) void act_qdq(const float* __restrict__ x,
                                               ushort* __restrict__ xq) {
    __shared__ float smn[4], smx[4];
    int row = blockIdx.x;
    const float* xr = x + (size_t)row * K_DIM;
    ushort* xo = xq + (size_t)row * K_DIM;
    int t = threadIdx.x;
    float4 v[4];
    float mn = FLT_MAX, mx = -FLT_MAX;
#pragma unroll
    for (int i = 0; i < 4; i++) {
        v[i] = ((const float4*)xr)[t + i * 256];
        mn = fminf(mn, fminf(fminf(v[i].x, v[i].y), fminf(v[i].z, v[i].w)));
        mx = fmaxf(mx, fmaxf(fmaxf(v[i].x, v[i].y), fmaxf(v[i].z, v[i].w)));
    }
#pragma unroll
    for (int s = 1; s < 64; s <<= 1) {
        mn = fminf(mn, __shfl_xor(mn, s));
        mx = fmaxf(mx, __shfl_xor(mx, s));
    }
    int w = t >> 6;
    if ((t & 63) == 0) { smn[w] = mn; smx[w] = mx; }
    __syncthreads();
    mn = fminf(fminf(smn[0], smn[1]), fminf(smn[2], smn[3]));
    mx = fmaxf(fmaxf(smx[0], smx[1]), fmaxf(smx[2], smx[3]));
    float scale = (mx - mn) / 255.0f;
    float zero  = -128.0f - rintf(mn / scale);
#pragma unroll
    for (int i = 0; i < 4; i++) {
        float e0 = v[i].x, e1 = v[i].y, e2 = v[i].z, e3 = v[i].w;
        ushort4 o;
        float q;
        q = fminf(fmaxf(rintf(e0 / scale) + zero, -128.0f), 127.0f); o.x = f2bf((q - zero) * scale);
        q = fminf(fmaxf(rintf(e1 / scale) + zero, -128.0f), 127.0f); o.y = f2bf((q - zero) * scale);
        q = fminf(fmaxf(rintf(e2 / scale) + zero, -128.0f), 127.0f); o.z = f2bf((q - zero) * scale);
        q = fminf(fmaxf(rintf(e3 / scale) + zero, -128.0f), 127.0f); o.w = f2bf((q - zero) * scale);
        ((ushort4*)xo)[t + i * 256] = o;
    }
}

// ---------------- kernel 3: 256x256 bf16 GEMM, 4 phases per 2 K-tiles ----------------
// Phase = [8x ds_read A (single set) + (ph1/ph3: 8x ds_read next-B, dbuf)] [stages]
//         [barrier] [lgkmcnt(0)] [32 MFMA] [vmcnt(N)] [barrier].
// 32 MFMA per barrier-pair amortizes the measured ~700cyc/phase structural floor.
// Stage slots (4/4/6/2) and waits vmcnt(6/8/6/8) audited: every forced drain is
// >=2 phases old; every read landed; every overwrite issue-after-death.
#define BM 256
#define BN 256
#define BK 64
#define NT (K_DIM / BK)   /* 64 K-tiles */

__global__ __launch_bounds__(512, 1) void gemm_bt8(const ushort* __restrict__ A,
                                                   const ushort* __restrict__ B,
                                                   float* __restrict__ C) {
    __shared__ __align__(16) ushort As[2][BM * BK];   // quarter rq at byte rq*8192
    __shared__ __align__(16) ushort Bs[2][BN * BK];

    const int nbx = N_DIM / BN;                 // 16
    const int nwg = (M_DIM / BM) * nbx;         // 512 (%8==0)
    int bid = blockIdx.x;
    bid = (bid & 7) * (nwg / 8) + (bid >> 3);   // bijective XCD swizzle
    int mb = bid / nbx, nb = bid % nbx;
    size_t m0 = (size_t)mb * BM, n0 = (size_t)nb * BN;

    const int t = threadIdx.x;
    const int w = t >> 6, lane = t & 63;
    const int wm = w >> 2, wn = w & 3;          // 2 x 4 wave grid; per-wave out 128x64
    const int lr = lane & 15;
    const int lk = (lane >> 4) << 3;

    const ushort* Ab = A + m0 * K_DIM;
    const ushort* Bb = B + n0 * K_DIM;

    // precomputed per-lane staging offsets for the 4 row-quarters (flat elem offset)
    int off_q[4];
    int dst_q[4];
#pragma unroll
    for (int rq = 0; rq < 4; rq++) {
        int base = rq * 8192 + w * 1024;
        int lb = base + lane * 16;
        int lg = SWZ(lb);
        off_q[rq] = (lg >> 7) * K_DIM + ((lg & 127) >> 1);
        dst_q[rq] = base;
    }

    // stage one 8KB quarter of tile T: qq 0-3 = A quarter, qq 4-7 = B quarter (qq-4).
    // qq is always a compile-time literal at call sites -> static indexing.
#define STAGE(T, qq) do {                                                         \
    int _d = (T) & 1;                                                             \
    const ushort* _g = ((qq) < 4 ? Ab : Bb);                                      \
    ushort* _l = ((qq) < 4 ? As[_d] : Bs[_d]);                                    \
    int _rq = (qq) & 3;                                                           \
    __builtin_amdgcn_global_load_lds(                                             \
        (const __attribute__((address_space(1))) unsigned int*)(_g + (size_t)off_q[_rq] + (T) * BK), \
        (__attribute__((address_space(3))) unsigned int*)((char*)_l + dst_q[_rq]),\
        16, 0, 0);                                                                \
  } while (0)

    f32x4 acc[8][4] = {};
    bf16x8 afr[4][2];      // single set: current phase's A half-tile
    bf16x8 bfr[2][4][2];   // [buffer parity][ni][kk]

#define LOADA(h, d) do {                                                          \
    _Pragma("unroll") for (int mf = 0; mf < 4; mf++)                              \
    _Pragma("unroll") for (int kk = 0; kk < 2; kk++) {                            \
        int row = (h) * 128 + (mf >> 1) * 64 + wm * 32 + (mf & 1) * 16 + lr;      \
        int lg = row * 128 + (kk * 32 + lk) * 2;                                  \
        afr[mf][kk] = *(const bf16x8*)((const char*)As[d] + SWZ(lg));             \
    } } while (0)
#define LOADB(d) do {                                                             \
    _Pragma("unroll") for (int ni = 0; ni < 4; ni++)                              \
    _Pragma("unroll") for (int kk = 0; kk < 2; kk++) {                            \
        int row = wn * 64 + ni * 16 + lr;                                         \
        int lg = row * 128 + (kk * 32 + lk) * 2;                                  \
        bfr[d][ni][kk] = *(const bf16x8*)((const char*)Bs[d] + SWZ(lg));          \
    } } while (0)

#define BAR1() do {                                                               \
    __builtin_amdgcn_s_barrier();                                                 \
    asm volatile("s_waitcnt lgkmcnt(0)" ::: "memory");                            \
    __builtin_amdgcn_sched_barrier(0);                                            \
  } while (0)

#define MFMA_PH(h, dB) do {                                                       \
    __builtin_amdgcn_s_setprio(1);                                                \
    _Pragma("unroll") for (int kk = 0; kk < 2; kk++)                              \
    _Pragma("unroll") for (int mf = 0; mf < 4; mf++)                              \
    _Pragma("unroll") for (int ni = 0; ni < 4; ni++)                              \
        acc[(h) * 4 + mf][ni] = __builtin_amdgcn_mfma_f32_16x16x32_bf16(          \
            afr[mf][kk], bfr[dB][ni][kk], acc[(h) * 4 + mf][ni], 0, 0, 0);        \
    __builtin_amdgcn_s_setprio(0);                                                \
  } while (0)

#define ENDPH(vm) do {                                                            \
    asm volatile("s_waitcnt " vm ::: "memory");                                   \
    __builtin_amdgcn_s_barrier();                                                 \
    __builtin_amdgcn_sched_barrier(0);                                            \
  } while (0)

    // prologue: tile0 all 8 quarters; tile1 B + A01 (the "(i-1)ph2" group); tile1 A23
    STAGE(0, 0); STAGE(0, 1); STAGE(0, 2); STAGE(0, 3);
    STAGE(0, 4); STAGE(0, 5); STAGE(0, 6); STAGE(0, 7);
    STAGE(1, 4); STAGE(1, 5); STAGE(1, 6); STAGE(1, 7); STAGE(1, 0); STAGE(1, 1);
    STAGE(1, 2); STAGE(1, 3);
    asm volatile("s_waitcnt vmcnt(8)" ::: "memory");   // tile0 fully landed
    __builtin_amdgcn_s_barrier();
    LOADB(0);                                          // B(tile0) frags

    // main: iters 0..NT/2-2; iter i computes tiles E=2i (ph0,ph1) and O=2i+1 (ph2,ph3)
#pragma unroll 1
    for (int i = 0; i < NT / 2 - 1; i++) {
        int E = 2 * i, O = 2 * i + 1;
        // ph0: MFMA E rows 0-127
        LOADA(0, 0);
        STAGE(E + 2, 0); STAGE(E + 2, 1); STAGE(E + 2, 4); STAGE(E + 2, 5);
        BAR1();
        MFMA_PH(0, 0);
        ENDPH("vmcnt(6)");
        // ph1: MFMA E rows 128-255; pre-read B(O)
        LOADA(1, 0);
        LOADB(1);
        STAGE(E + 2, 6); STAGE(E + 2, 7); STAGE(E + 2, 2); STAGE(E + 2, 3);
        BAR1();
        MFMA_PH(1, 0);
        ENDPH("vmcnt(8)");
        // ph2: MFMA O rows 0-127
        LOADA(0, 1);
        STAGE(O + 2, 4); STAGE(O + 2, 5); STAGE(O + 2, 6); STAGE(O + 2, 7);
        STAGE(O + 2, 0); STAGE(O + 2, 1);
        BAR1();
        MFMA_PH(0, 1);
        ENDPH("vmcnt(6)");
        // ph3: MFMA O rows 128-255; pre-read B(E+2)
        LOADA(1, 1);
        LOADB(0);
        STAGE(O + 2, 2); STAGE(O + 2, 3);
        BAR1();
        MFMA_PH(1, 1);
        ENDPH("vmcnt(8)");
    }

    // tail: tiles NT-2 (buf0), NT-1 (buf1); no stages; explicit drains then barrier-free
    LOADA(0, 0);
    BAR1();
    MFMA_PH(0, 0);
    ENDPH("vmcnt(2)");      // drain B(NT-1)+A01(NT-1)
    LOADA(1, 0);
    LOADB(1);
    BAR1();
    MFMA_PH(1, 0);
    ENDPH("vmcnt(0)");      // drain A23(NT-1)
    LOADA(0, 1);
    asm volatile("s_waitcnt lgkmcnt(0)" ::: "memory");
    __builtin_amdgcn_sched_barrier(0);
    MFMA_PH(0, 1);
    LOADA(1, 1);
    asm volatile("s_waitcnt lgkmcnt(0)" ::: "memory");
    __builtin_amdgcn_sched_barrier(0);
    MFMA_PH(1, 1);
#undef STAGE
#undef LOADA
#undef LOADB
#undef BAR1
#undef MFMA_PH
#undef ENDPH

    // C write: acc[mi][ni] -> row = m0 + (mi>>1)*64 + wm*32 + (mi&1)*16 + fq*4 + r
    int fq = lane >> 4;
#pragma unroll
    for (int mi = 0; mi < 8; mi++) {
#pragma unroll
        for (int ni = 0; ni < 4; ni++) {
#pragma unroll
            for (int r = 0; r < 4; r++) {
                size_t crow = m0 + (mi >> 1) * 64 + wm * 32 + (mi & 1) * 16 + fq * 4 + r;
                C[crow * N_DIM + n0 + wn * 64 + ni * 16 + lr] = acc[mi][ni][r];
            }
        }
    }
}

extern "C" void kernel_launch(void* const* d_in, const int* in_sizes, int n_in,
                              void* d_out, int out_size, void* d_ws, size_t ws_size,
                              hipStream_t stream) {
    const float* x = (const float*)d_in[0];
    const float* w = (const float*)d_in[1];
    float* out = (float*)d_out;

    ushort* wq = (ushort*)d_ws;                                        // 32 MiB
    ushort* xq = (ushort*)((char*)d_ws + (size_t)N_DIM * K_DIM * 2);   // 64 MiB

    hipLaunchKernelGGL(w_dequant, dim3((N_DIM * K_DIM / 128) / 4), dim3(256), 0, stream, w, wq);
    hipLaunchKernelGGL(act_qdq, dim3(M_DIM), dim3(256), 0, stream, x, xq);
    hipLaunchKernelGGL(gemm_bt8, dim3((M_DIM / BM) * (N_DIM / BN)), dim3(512), 0, stream, xq, wq, out);
}